// Round 17
// baseline (292.501 us; speedup 1.0000x reference)
//
#include <hip/hip_runtime.h>
#include <hip/hip_bf16.h>

#define B_    32
#define C_    256
#define HWI   4096   // 64*64
#define NW    65536  // elems per weight matrix (256x256)
#define SHIFT 20.0f  // fixed softmax shift

typedef short short8 __attribute__((ext_vector_type(8)));
typedef short s4v    __attribute__((ext_vector_type(4)));
typedef float f32x4  __attribute__((ext_vector_type(4)));
typedef _Float16 half8 __attribute__((ext_vector_type(8)));

#define MFMAH(a, b, c) __builtin_amdgcn_mfma_f32_16x16x32_f16(a, b, c, 0, 0, 0)

// fp16 helpers (RNE casts)
__device__ __forceinline__ unsigned short f2h(float x) {
    _Float16 t = (_Float16)x;
    return __builtin_bit_cast(unsigned short, t);
}
__device__ __forceinline__ float h2f(unsigned short b) {
    return (float)__builtin_bit_cast(_Float16, b);
}
// bf16 (for P only — needs > fp16 range)
__device__ __forceinline__ unsigned short f2bf(float x) {
    __hip_bfloat16 t = __float2bfloat16(x);
    return *reinterpret_cast<unsigned short*>(&t);
}
__device__ __forceinline__ float bf2f(unsigned short b) {
    return __uint_as_float((unsigned)b << 16);
}

// ---------------------------------------------------------------------------
// Convert ALL 4 weight matrices fp32 -> SINGLE fp16, MFMA-fragment-linear:
// flat = (o>>4)*4096 + (k>>3)*128 + (o&15)*8 + (k&7). grid (32, 4)
// ---------------------------------------------------------------------------
__global__ __launch_bounds__(256)
void wsingle4_k(const float* __restrict__ w0, const float* __restrict__ w1,
                const float* __restrict__ w2, const float* __restrict__ w3,
                short* __restrict__ dst)
{
    const int m = blockIdx.y;
    const float* w = (m == 0) ? w0 : (m == 1) ? w1 : (m == 2) ? w2 : w3;
    short* wd = dst + (size_t)m * NW;

    const int g  = blockIdx.x * 256 + threadIdx.x;
    const int o  = g >> 5, k8 = g & 31;
    const float* src = w + o * 256 + k8 * 8;
    const int d = (o >> 4) * 4096 + k8 * 128 + (o & 15) * 8;
    short8 h8;
    #pragma unroll
    for (int j = 0; j < 8; ++j) h8[j] = (short)f2h(src[j]);
    *(short8*)(wd + d) = h8;
}

// ---------------------------------------------------------------------------
// conv building blocks — single-fp16 x in LDS (32 KB), 1-term MFMA
// ---------------------------------------------------------------------------
__device__ __forceinline__ void stage_load(const float* __restrict__ inb,
                                           int half, int sp, int kq, float* v)
{
    #pragma unroll
    for (int r = 0; r < 4; ++r) {
        const int k8 = half * 16 + r * 4 + kq;
        const float* gx = inb + (size_t)(k8 * 8) * HWI + sp;
        #pragma unroll
        for (int j = 0; j < 8; ++j) v[r * 8 + j] = gx[(size_t)j * HWI];
    }
}

__device__ __forceinline__ void stage_write(int half, int sp, int kq,
        const float* v, short (*xs)[256])
{
    #pragma unroll
    for (int r = 0; r < 4; ++r) {
        const int k8 = half * 16 + r * 4 + kq;
        short8 h8;
        #pragma unroll
        for (int j = 0; j < 8; ++j) h8[j] = (short)f2h(v[r * 8 + j]);
        const int ch = (k8 ^ (sp & 7)) * 8;   // XOR stays within half's chunk range
        *(short8*)&xs[sp][ch] = h8;
    }
}

__device__ __forceinline__ void load_a1(half8 a[4], const short* __restrict__ w,
                                        int s, int lane, int o16b)
{
    const int k8 = s * 4 + (lane >> 4);
    #pragma unroll
    for (int i = 0; i < 4; ++i)
        a[i] = *(const half8*)(w + ((o16b + i) * 32 + k8) * 128 + (lane & 15) * 8);
}

__device__ __forceinline__ void load_b1(half8 bq[4], int s, int lane,
                                        const short (*xs)[256])
{
    const int k8 = s * 4 + (lane >> 4);
    #pragma unroll
    for (int f = 0; f < 4; ++f) {
        const int pr = f * 16 + (lane & 15);
        bq[f] = *(const half8*)&xs[pr][(k8 ^ (pr & 7)) * 8];
    }
}

__device__ __forceinline__ void mfma16(const half8 a[4], const half8 bq[4],
                                       f32x4 acc[4][4])
{
    __builtin_amdgcn_s_setprio(1);
    #pragma unroll
    for (int i = 0; i < 4; ++i)
        #pragma unroll
        for (int f = 0; f < 4; ++f)
            acc[i][f] = MFMAH(a[i], bq[f], acc[i][f]);
    __builtin_amdgcn_s_setprio(0);
}

// A-only prefetch step (conv0 in convQVK, convY): 128-VGPR sweet spot while
// the staging buffer v[32] is live.
#define QSTEP(Acur, Anext, wnext, snext, s, accv)           \
    load_a1(Anext, wnext, snext, lane, o16b);               \
    load_b1(Bq, s, lane, xs);                               \
    mfma16(Acur, Bq, accv);

// A+B prefetch step (conv1/conv2: v[32] dead, B0/B1 reuse its registers)
#define QS2(Acur, Anext, wnext, sa, Bcur, Bnext, sb, accv)  \
    load_a1(Anext, wnext, sa, lane, o16b);                  \
    load_b1(Bnext, sb, lane, xs);                           \
    mfma16(Acur, Bcur, accv);

__device__ __forceinline__ void conv_epi_h16(const f32x4 acc[4][4],
        const float* __restrict__ bias, unsigned short* __restrict__ ob,
        int p0, int wv, int lane)
{
    const int pl = p0 + (lane & 15);
    #pragma unroll
    for (int i = 0; i < 4; ++i)
        #pragma unroll
        for (int r = 0; r < 4; ++r) {
            const int o = wv * 64 + i * 16 + (lane >> 4) * 4 + r;
            const float bz = bias[o];
            #pragma unroll
            for (int f = 0; f < 4; ++f)
                ob[(size_t)o * HWI + pl + f * 16] = f2h(acc[i][f][r] + bz);
        }
}

// ---------------------------------------------------------------------------
// Fused q,v,k convs (fp32 in, 1-term fp16 MFMA).
// conv0: A-prefetch only (v live). conv1/conv2: A+B prefetch (v dead ->
// B0/B1 live in v's registers; VGPR should stay ~128). x shared across
// convs => B(0) identical for all three: conv1's tail prefetches conv2's
// B(0); only conv1 entry has one exposed B load.
// grid: (HWI/64, B_), XCD-chunked swizzle. 32 KB LDS, plain bounds.
// ---------------------------------------------------------------------------
__global__ __launch_bounds__(256)
void convQVK_k(const float* __restrict__ in, const short* __restrict__ wb,
               const float* __restrict__ b0, const float* __restrict__ b1,
               const float* __restrict__ b2,
               unsigned short* __restrict__ f1, unsigned short* __restrict__ f2,
               unsigned short* __restrict__ g1)
{
    __shared__ short xs[64][256];   // 32 KB, fp16 [p][k], chunk-XOR swizzle

    const int tid  = threadIdx.x;
    const int lane = tid & 63;
    const int wv   = tid >> 6;

    const int id    = blockIdx.y * gridDim.x + blockIdx.x;
    const int chunk = (gridDim.x * gridDim.y) >> 3;
    const int nid   = (id & 7) * chunk + (id >> 3);
    const int p0    = (nid & 63) * 64;
    const int b     = nid >> 6;

    const float* inb = in + (size_t)b * C_ * HWI + p0;
    const int sp = tid & 63, kq = tid >> 6;
    const int o16b = wv * 4;
    const size_t obase = (size_t)b * C_ * HWI;

    const short* w0p = wb;
    const short* w1p = wb + (size_t)NW;
    const short* w2p = wb + 2 * (size_t)NW;

    half8 A0[4], A1[4], Bq[4];
    load_a1(A0, w0p, 0, lane, o16b);     // earliest prefetch

    float v[32];
    stage_load(inb, 0, sp, kq, v);
    stage_write(0, sp, kq, v, xs);
    __syncthreads();

    stage_load(inb, 1, sp, kq, v);       // half-1 HBM loads in flight

    // conv0 (q -> f1): A-prefetch only (v[] live)
    f32x4 acc[4][4] = {};
    QSTEP(A0, A1, w0p, 1, 0, acc)
    QSTEP(A1, A0, w0p, 2, 1, acc)
    QSTEP(A0, A1, w0p, 3, 2, acc)
    QSTEP(A1, A0, w0p, 4, 3, acc)        // prefetch s=4 across the barrier
    stage_write(1, sp, kq, v, xs);       // v[] DEAD after this
    __syncthreads();
    QSTEP(A0, A1, w0p, 5, 4, acc)
    QSTEP(A1, A0, w0p, 6, 5, acc)
    QSTEP(A0, A1, w0p, 7, 6, acc)
    QSTEP(A1, A0, w1p, 0, 7, acc)        // prefetch conv1 A(0)

    half8 B0[4], B1[4];                  // lives in v's dead registers
    load_b1(B0, 0, lane, xs);            // conv1's B(0): the one exposed load
    conv_epi_h16(acc, b0, f1 + obase, p0, wv, lane);

    // conv1 (v -> f2): A+B prefetch
    {
        f32x4 acc2[4][4] = {};
        QS2(A0, A1, w1p, 1, B0, B1, 1, acc2)
        QS2(A1, A0, w1p, 2, B1, B0, 2, acc2)
        QS2(A0, A1, w1p, 3, B0, B1, 3, acc2)
        QS2(A1, A0, w1p, 4, B1, B0, 4, acc2)
        QS2(A0, A1, w1p, 5, B0, B1, 5, acc2)
        QS2(A1, A0, w1p, 6, B1, B0, 6, acc2)
        QS2(A0, A1, w1p, 7, B0, B1, 7, acc2)
        QS2(A1, A0, w2p, 0, B1, B0, 0, acc2)   // prefetch conv2 A(0), B(0)
        conv_epi_h16(acc2, b1, f2 + obase, p0, wv, lane);
    }

    // conv2 (k -> g1): A+B prefetch
    {
        f32x4 acc3[4][4] = {};
        QS2(A0, A1, w2p, 1, B0, B1, 1, acc3)
        QS2(A1, A0, w2p, 2, B1, B0, 2, acc3)
        QS2(A0, A1, w2p, 3, B0, B1, 3, acc3)
        QS2(A1, A0, w2p, 4, B1, B0, 4, acc3)
        QS2(A0, A1, w2p, 5, B0, B1, 5, acc3)
        QS2(A1, A0, w2p, 6, B1, B0, 6, acc3)
        QS2(A0, A1, w2p, 7, B0, B1, 7, acc3)
        QS2(A1, A0, w2p, 0, B1, B0, 0, acc3)   // tail harmless
        conv_epi_h16(acc3, b2, g1 + obase, p0, wv, lane);
    }
}

// ---------------------------------------------------------------------------
// Final conv: fp16 input, 1-term fp16 MFMA, A-prefetch, +bias +residual
// -> fp32. 32 KB LDS, plain bounds. EXACT round-15/16 form. grid: (HWI/64, B_)
// ---------------------------------------------------------------------------
__global__ __launch_bounds__(256)
void convY_k(const unsigned short* __restrict__ in, const float* __restrict__ res,
             const short* __restrict__ w, const float* __restrict__ bias,
             float* __restrict__ out)
{
    __shared__ short xs[64][256];   // 32 KB

    const int tid  = threadIdx.x;
    const int lane = tid & 63;
    const int wv   = tid >> 6;

    const int id    = blockIdx.y * gridDim.x + blockIdx.x;
    const int chunk = (gridDim.x * gridDim.y) >> 3;
    const int nid   = (id & 7) * chunk + (id >> 3);
    const int p0    = (nid & 63) * 64;
    const int b     = nid >> 6;

    const unsigned short* inb = in + (size_t)b * C_ * HWI + p0;
    const int sp = tid & 63, kq = tid >> 6;
    const int o16b = wv * 4;

    half8 A0[4], A1[4], Bq[4];
    load_a1(A0, w, 0, lane, o16b);

    unsigned short uv[32];

    // stage half 0
    #pragma unroll
    for (int r = 0; r < 4; ++r) {
        const int k8 = r * 4 + kq;
        #pragma unroll
        for (int j = 0; j < 8; ++j) uv[r * 8 + j] = inb[(size_t)(k8 * 8 + j) * HWI + sp];
    }
    #pragma unroll
    for (int r = 0; r < 4; ++r) {
        const int k8 = r * 4 + kq;
        short8 v8;
        #pragma unroll
        for (int j = 0; j < 8; ++j) v8[j] = (short)uv[r * 8 + j];
        *(short8*)&xs[sp][(k8 ^ (sp & 7)) * 8] = v8;
    }
    __syncthreads();

    // issue half-1 loads
    #pragma unroll
    for (int r = 0; r < 4; ++r) {
        const int k8 = 16 + r * 4 + kq;
        #pragma unroll
        for (int j = 0; j < 8; ++j) uv[r * 8 + j] = inb[(size_t)(k8 * 8 + j) * HWI + sp];
    }

    f32x4 acc[4][4] = {};
    QSTEP(A0, A1, w, 1, 0, acc)
    QSTEP(A1, A0, w, 2, 1, acc)
    QSTEP(A0, A1, w, 3, 2, acc)
    QSTEP(A1, A0, w, 4, 3, acc)

    #pragma unroll
    for (int r = 0; r < 4; ++r) {
        const int k8 = 16 + r * 4 + kq;
        short8 v8;
        #pragma unroll
        for (int j = 0; j < 8; ++j) v8[j] = (short)uv[r * 8 + j];
        *(short8*)&xs[sp][(k8 ^ (sp & 7)) * 8] = v8;
    }
    __syncthreads();

    QSTEP(A0, A1, w, 5, 4, acc)
    QSTEP(A1, A0, w, 6, 5, acc)
    QSTEP(A0, A1, w, 7, 6, acc)
    QSTEP(A1, A0, w, 0, 7, acc)   // tail harmless

    float* ob = out + (size_t)b * C_ * HWI;
    const float* rb = res + (size_t)b * C_ * HWI;
    const int pl = p0 + (lane & 15);
    #pragma unroll
    for (int i = 0; i < 4; ++i)
        #pragma unroll
        for (int r = 0; r < 4; ++r) {
            const int o = wv * 64 + i * 16 + (lane >> 4) * 4 + r;
            const float bz = bias[o];
            #pragma unroll
            for (int f = 0; f < 4; ++f) {
                const size_t off = (size_t)o * HWI + pl + f * 16;
                ob[off] = acc[i][f][r] + bz + rb[off];
            }
        }
}

// ---------------------------------------------------------------------------
// zgemmP: per-(b,c) z = f1 @ f2^T via 1-term fp16 MFMA, fused exp epilogue
// -> P = e^(z-SHIFT) bf16 (range!), LDS-transposed coalesced store.
// grid (C_, B_), 256 thr (4 waves), 16 KB LDS.
// ---------------------------------------------------------------------------
__global__ __launch_bounds__(256)
void zgemmP_k(const unsigned short* __restrict__ f1,
              const unsigned short* __restrict__ f2,
              unsigned short* __restrict__ P)
{
    __shared__ short am[64 * 64], bm[64 * 64];   // 16 KB

    const int tid = threadIdx.x, lane = tid & 63, wv = tid >> 6;
    const int c = blockIdx.x, b = blockIdx.y;
    const size_t base = ((size_t)b * C_ + c) * HWI;

    const int r = tid >> 2, q8 = (tid & 3) * 2;
    {
        const size_t g0 = base + r * 64 + q8 * 8;
        short8 v0 = *(const short8*)(f1 + g0), v1 = *(const short8*)(f1 + g0 + 8);
        short8 u0 = *(const short8*)(f2 + g0), u1 = *(const short8*)(f2 + g0 + 8);
        const int c0 = (q8 ^ (r & 7)) * 8, c1 = ((q8 + 1) ^ (r & 7)) * 8;
        *(short8*)&am[r * 64 + c0] = v0;  *(short8*)&am[r * 64 + c1] = v1;
        *(short8*)&bm[r * 64 + c0] = u0;  *(short8*)&bm[r * 64 + c1] = u1;
    }
    __syncthreads();

    f32x4 acc[4] = {};
    const int m = wv * 16 + (lane & 15);
    #pragma unroll
    for (int s = 0; s < 2; ++s) {
        const int k8 = s * 4 + (lane >> 4);
        half8 a = *(const half8*)&am[m * 64 + (k8 ^ (m & 7)) * 8];
        #pragma unroll
        for (int nf = 0; nf < 4; ++nf) {
            const int n = nf * 16 + (lane & 15);
            half8 bb = *(const half8*)&bm[n * 64 + (k8 ^ (n & 7)) * 8];
            acc[nf] = MFMAH(a, bb, acc[nf]);
        }
    }
    __syncthreads();   // all frag reads done; reuse am as transpose buffer

    short* pt = am;
    #pragma unroll
    for (int nf = 0; nf < 4; ++nf)
        #pragma unroll
        for (int rr = 0; rr < 4; ++rr) {
            const int h = wv * 16 + (lane >> 4) * 4 + rr;
            const int g = nf * 16 + (lane & 15);
            const float pv = __expf(acc[nf][rr] - SHIFT);
            pt[h * 64 + (((g >> 3) ^ (h & 7)) * 8) + (g & 7)] = (short)f2bf(pv);
        }
    __syncthreads();
    {
        const size_t g0 = base + r * 64 + q8 * 8;
        const int c0 = (q8 ^ (r & 7)) * 8, c1 = ((q8 + 1) ^ (r & 7)) * 8;
        *(short8*)(P + g0)     = *(const short8*)&pt[r * 64 + c0];
        *(short8*)(P + g0 + 8) = *(const short8*)&pt[r * 64 + c1];
    }
}

// ---------------------------------------------------------------------------
// statsP: sr[b,p] = 1 / sum_c P[b,c,p]   (P bf16)
// ---------------------------------------------------------------------------
__global__ __launch_bounds__(256)
void statsP_k(const unsigned short* __restrict__ P, float* __restrict__ sr)
{
    const int qidx = blockIdx.x * 256 + threadIdx.x;
    const int b = qidx >> 12, p = qidx & 4095;
    const unsigned short* pp = P + (size_t)b * C_ * HWI + p;
    float s = 0.f;
    for (int c0 = 0; c0 < C_; c0 += 8) {
        float e = 0.f;
        #pragma unroll
        for (int j = 0; j < 8; ++j) e += bf2f(pp[(size_t)(c0 + j) * HWI]);
        s += e;
    }
    sr[qidx] = 1.0f / s;
}

// ---------------------------------------------------------------------------
// pvP: out1 = (P .* sr) @ g1 via 1-term fp16 MFMA. P*sr in [0,1] -> fp16.
// grid (C_, B_), 16 KB LDS. out1 fp16.
// ---------------------------------------------------------------------------
__global__ __launch_bounds__(256)
void pvP_k(const unsigned short* __restrict__ P, const float* __restrict__ sr,
           const unsigned short* __restrict__ g1, unsigned short* __restrict__ out1)
{
    __shared__ short pa[64 * 64], gb[64 * 64];

    const int tid = threadIdx.x, lane = tid & 63, wv = tid >> 6;
    const int c = blockIdx.x, b = blockIdx.y;
    const size_t base = ((size_t)b * C_ + c) * HWI;

    const int r = tid >> 2, q8 = (tid & 3) * 2;
    {   // A = P' = P * sr  (fp16)  [h][g]
        const size_t g0 = base + r * 64 + q8 * 8;
        const float* srp = sr + (size_t)b * HWI + r * 64 + q8 * 8;
        short8 p0 = *(const short8*)(P + g0), p1 = *(const short8*)(P + g0 + 8);
        short8 w0, w1;
        #pragma unroll
        for (int j = 0; j < 8; ++j) {
            w0[j] = (short)f2h(bf2f((unsigned short)p0[j]) * srp[j]);
            w1[j] = (short)f2h(bf2f((unsigned short)p1[j]) * srp[8 + j]);
        }
        const int c0 = (q8 ^ (r & 7)) * 8, c1 = ((q8 + 1) ^ (r & 7)) * 8;
        *(short8*)&pa[r * 64 + c0] = w0;
        *(short8*)&pa[r * 64 + c1] = w1;
    }
    {   // B = g1^T : gb[w][g]
        const int w = tid & 63, kq = tid >> 6;
        short8 t0, t1;
        #pragma unroll
        for (int j = 0; j < 8; ++j) t0[j] = (short)g1[base + (size_t)(kq * 16 + j) * 64 + w];
        #pragma unroll
        for (int j = 0; j < 8; ++j) t1[j] = (short)g1[base + (size_t)(kq * 16 + 8 + j) * 64 + w];
        const int c0 = ((kq * 2) ^ (w & 7)) * 8, c1 = ((kq * 2 + 1) ^ (w & 7)) * 8;
        *(short8*)&gb[w * 64 + c0] = t0;
        *(short8*)&gb[w * 64 + c1] = t1;
    }
    __syncthreads();

    f32x4 acc[4] = {};
    const int m = wv * 16 + (lane & 15);
    #pragma unroll
    for (int s = 0; s < 2; ++s) {
        const int k8 = s * 4 + (lane >> 4);
        half8 aa = *(const half8*)&pa[m * 64 + (k8 ^ (m & 7)) * 8];
        #pragma unroll
        for (int nf = 0; nf < 4; ++nf) {
            const int n = nf * 16 + (lane & 15);
            half8 bb = *(const half8*)&gb[n * 64 + (k8 ^ (n & 7)) * 8];
            acc[nf] = MFMAH(aa, bb, acc[nf]);
        }
    }
    __syncthreads();

    short* ot = pa;
    #pragma unroll
    for (int nf = 0; nf < 4; ++nf)
        #pragma unroll
        for (int rr = 0; rr < 4; ++rr) {
            const int h = wv * 16 + (lane >> 4) * 4 + rr;
            const int w = nf * 16 + (lane & 15);
            ot[h * 64 + (((w >> 3) ^ (h & 7)) * 8) + (w & 7)] = (short)f2h(acc[nf][rr]);
        }
    __syncthreads();
    {
        const size_t g0 = base + r * 64 + q8 * 8;
        const int c0 = (q8 ^ (r & 7)) * 8, c1 = ((q8 + 1) ^ (r & 7)) * 8;
        *(short8*)(out1 + g0)     = *(const short8*)&ot[r * 64 + c0];
        *(short8*)(out1 + g0 + 8) = *(const short8*)&ot[r * 64 + c1];
    }
}

// ---------------------------------------------------------------------------
extern "C" void kernel_launch(void* const* d_in, const int* in_sizes, int n_in,
                              void* d_out, int out_size, void* d_ws, size_t ws_size,
                              hipStream_t stream)
{
    (void)in_sizes; (void)n_in; (void)out_size;
    const float* x  = (const float*)d_in[0];
    const float* wq = (const float*)d_in[1];
    const float* bq = (const float*)d_in[2];
    const float* wv = (const float*)d_in[3];
    const float* bv = (const float*)d_in[4];
    const float* wk = (const float*)d_in[5];
    const float* bk = (const float*)d_in[6];
    const float* wy = (const float*)d_in[7];
    const float* by = (const float*)d_in[8];
    float* out = (float*)d_out;

    const size_t N  = (size_t)B_ * C_ * HWI;   // 33,554,432
    const size_t NS = (size_t)B_ * HWI;        // 131,072

    char* wsb = (char*)d_ws;
    short* wsp = (short*)wsb;
    const size_t wbytes = 4 * (size_t)NW * sizeof(short);   // 512 KB
    char* fb = wsb + wbytes;

    dim3 blk(256);
    hipLaunchKernelGGL(wsingle4_k, dim3(32, 4), blk, 0, stream, wq, wv, wk, wy, wsp);
    const short* wqvk = wsp;                 // q,v,k (3 x NW)
    const short* wyp  = wsp + 3 * (size_t)NW;

    dim3 cgrid(HWI / 64, B_);     // 2048 blocks
    dim3 zgrid(C_, B_);           // 8192 blocks
    dim3 sgrid((unsigned)(NS / 256));

    // Layout A: everything in ws. Layout B: f2,P live in d_out (dead until convY)
    const bool bigA = ws_size >= wbytes + 8 * N + 4 * NS;

    unsigned short *f1, *f2, *g1, *P, *o1;
    float* sr;
    if (bigA) {
        f1 = (unsigned short*)fb;
        f2 = (unsigned short*)(fb + 2 * N);
        g1 = (unsigned short*)(fb + 4 * N);
        P  = (unsigned short*)(fb + 6 * N);
        sr = (float*)(fb + 8 * N);
    } else {
        f1 = (unsigned short*)fb;
        g1 = (unsigned short*)(fb + 2 * N);
        sr = (float*)(fb + 4 * N);
        f2 = (unsigned short*)d_out;          // d_out = 4N bytes total
        P  = (unsigned short*)d_out + N;
    }
    o1 = f1;   // reuse (f1 dead after zgemmP)

    hipLaunchKernelGGL(convQVK_k, cgrid, blk, 0, stream,
                       x, wqvk, bq, bv, bk, f1, f2, g1);
    hipLaunchKernelGGL(zgemmP_k, zgrid, blk, 0, stream, f1, f2, P);
    hipLaunchKernelGGL(statsP_k, sgrid, blk, 0, stream, P, sr);
    hipLaunchKernelGGL(pvP_k,    zgrid, blk, 0, stream, P, sr, g1, o1);
    hipLaunchKernelGGL(convY_k,  cgrid, blk, 0, stream, o1, x, wyp, by, out);
}

// Round 18
// 270.158 us; speedup vs baseline: 1.0827x; 1.0827x over previous
//
#include <hip/hip_runtime.h>
#include <hip/hip_bf16.h>

#define B_    32
#define C_    256
#define HWI   4096   // 64*64
#define NW    65536  // elems per weight matrix (256x256)
#define SHIFT 20.0f  // fixed softmax shift

typedef short short8 __attribute__((ext_vector_type(8)));
typedef short s4v    __attribute__((ext_vector_type(4)));
typedef float f32x4  __attribute__((ext_vector_type(4)));
typedef _Float16 half8 __attribute__((ext_vector_type(8)));

#define MFMAH(a, b, c) __builtin_amdgcn_mfma_f32_16x16x32_f16(a, b, c, 0, 0, 0)

// fp16 helpers (RNE casts)
__device__ __forceinline__ unsigned short f2h(float x) {
    _Float16 t = (_Float16)x;
    return __builtin_bit_cast(unsigned short, t);
}
__device__ __forceinline__ float h2f(unsigned short b) {
    return (float)__builtin_bit_cast(_Float16, b);
}
// bf16 (for P only — needs > fp16 range)
__device__ __forceinline__ unsigned short f2bf(float x) {
    __hip_bfloat16 t = __float2bfloat16(x);
    return *reinterpret_cast<unsigned short*>(&t);
}
__device__ __forceinline__ float bf2f(unsigned short b) {
    return __uint_as_float((unsigned)b << 16);
}

// ---------------------------------------------------------------------------
// Convert ALL 4 weight matrices fp32 -> SINGLE fp16, MFMA-fragment-linear:
// flat = (o>>4)*4096 + (k>>3)*128 + (o&15)*8 + (k&7). grid (32, 4)
// ---------------------------------------------------------------------------
__global__ __launch_bounds__(256)
void wsingle4_k(const float* __restrict__ w0, const float* __restrict__ w1,
                const float* __restrict__ w2, const float* __restrict__ w3,
                short* __restrict__ dst)
{
    const int m = blockIdx.y;
    const float* w = (m == 0) ? w0 : (m == 1) ? w1 : (m == 2) ? w2 : w3;
    short* wd = dst + (size_t)m * NW;

    const int g  = blockIdx.x * 256 + threadIdx.x;
    const int o  = g >> 5, k8 = g & 31;
    const float* src = w + o * 256 + k8 * 8;
    const int d = (o >> 4) * 4096 + k8 * 128 + (o & 15) * 8;
    short8 h8;
    #pragma unroll
    for (int j = 0; j < 8; ++j) h8[j] = (short)f2h(src[j]);
    *(short8*)(wd + d) = h8;
}

// ---------------------------------------------------------------------------
// conv building blocks — single-fp16 x in LDS (32 KB), 1-term MFMA
// ---------------------------------------------------------------------------
__device__ __forceinline__ void stage_load(const float* __restrict__ inb,
                                           int half, int sp, int kq, float* v)
{
    #pragma unroll
    for (int r = 0; r < 4; ++r) {
        const int k8 = half * 16 + r * 4 + kq;
        const float* gx = inb + (size_t)(k8 * 8) * HWI + sp;
        #pragma unroll
        for (int j = 0; j < 8; ++j) v[r * 8 + j] = gx[(size_t)j * HWI];
    }
}

__device__ __forceinline__ void stage_write(int half, int sp, int kq,
        const float* v, short (*xs)[256])
{
    #pragma unroll
    for (int r = 0; r < 4; ++r) {
        const int k8 = half * 16 + r * 4 + kq;
        short8 h8;
        #pragma unroll
        for (int j = 0; j < 8; ++j) h8[j] = (short)f2h(v[r * 8 + j]);
        const int ch = (k8 ^ (sp & 7)) * 8;   // XOR stays within half's chunk range
        *(short8*)&xs[sp][ch] = h8;
    }
}

__device__ __forceinline__ void load_a1(half8 a[4], const short* __restrict__ w,
                                        int s, int lane, int o16b)
{
    const int k8 = s * 4 + (lane >> 4);
    #pragma unroll
    for (int i = 0; i < 4; ++i)
        a[i] = *(const half8*)(w + ((o16b + i) * 32 + k8) * 128 + (lane & 15) * 8);
}

__device__ __forceinline__ void load_b1(half8 bq[4], int s, int lane,
                                        const short (*xs)[256])
{
    const int k8 = s * 4 + (lane >> 4);
    #pragma unroll
    for (int f = 0; f < 4; ++f) {
        const int pr = f * 16 + (lane & 15);
        bq[f] = *(const half8*)&xs[pr][(k8 ^ (pr & 7)) * 8];
    }
}

__device__ __forceinline__ void mfma16(const half8 a[4], const half8 bq[4],
                                       f32x4 acc[4][4])
{
    __builtin_amdgcn_s_setprio(1);
    #pragma unroll
    for (int i = 0; i < 4; ++i)
        #pragma unroll
        for (int f = 0; f < 4; ++f)
            acc[i][f] = MFMAH(a[i], bq[f], acc[i][f]);
    __builtin_amdgcn_s_setprio(0);
}

// A-only prefetch step: the proven 128-VGPR sweet spot. B-prefetch (any
// form: r15 direct, r17 lifetime-reuse) pushes VGPR to 136 -> crosses the
// 128 occupancy boundary -> loses a wave/SIMD -> net regression.
#define QSTEP(Acur, Anext, wnext, snext, s, accv)           \
    load_a1(Anext, wnext, snext, lane, o16b);               \
    load_b1(Bq, s, lane, xs);                               \
    mfma16(Acur, Bq, accv);

__device__ __forceinline__ void conv_epi_h16(const f32x4 acc[4][4],
        const float* __restrict__ bias, unsigned short* __restrict__ ob,
        int p0, int wv, int lane)
{
    const int pl = p0 + (lane & 15);
    #pragma unroll
    for (int i = 0; i < 4; ++i)
        #pragma unroll
        for (int r = 0; r < 4; ++r) {
            const int o = wv * 64 + i * 16 + (lane >> 4) * 4 + r;
            const float bz = bias[o];
            #pragma unroll
            for (int f = 0; f < 4; ++f)
                ob[(size_t)o * HWI + pl + f * 16] = f2h(acc[i][f][r] + bz);
        }
}

// ---------------------------------------------------------------------------
// Fused q,v,k convs (fp32 in, 1-term fp16 MFMA, A-prefetch pipeline).
// f1,f2,g1 out single fp16. 32 KB LDS, plain bounds. EXACT round-16 form
// (measured 148 us @ VGPR 128). grid: (HWI/64, B_), XCD-chunked swizzle.
// ---------------------------------------------------------------------------
__global__ __launch_bounds__(256)
void convQVK_k(const float* __restrict__ in, const short* __restrict__ wb,
               const float* __restrict__ b0, const float* __restrict__ b1,
               const float* __restrict__ b2,
               unsigned short* __restrict__ f1, unsigned short* __restrict__ f2,
               unsigned short* __restrict__ g1)
{
    __shared__ short xs[64][256];   // 32 KB, fp16 [p][k], chunk-XOR swizzle

    const int tid  = threadIdx.x;
    const int lane = tid & 63;
    const int wv   = tid >> 6;

    const int id    = blockIdx.y * gridDim.x + blockIdx.x;
    const int chunk = (gridDim.x * gridDim.y) >> 3;
    const int nid   = (id & 7) * chunk + (id >> 3);
    const int p0    = (nid & 63) * 64;
    const int b     = nid >> 6;

    const float* inb = in + (size_t)b * C_ * HWI + p0;
    const int sp = tid & 63, kq = tid >> 6;
    const int o16b = wv * 4;
    const size_t obase = (size_t)b * C_ * HWI;

    const short* w0p = wb;
    const short* w1p = wb + (size_t)NW;
    const short* w2p = wb + 2 * (size_t)NW;

    half8 A0[4], A1[4], Bq[4];
    load_a1(A0, w0p, 0, lane, o16b);     // earliest prefetch

    float v[32];
    stage_load(inb, 0, sp, kq, v);
    stage_write(0, sp, kq, v, xs);
    __syncthreads();

    stage_load(inb, 1, sp, kq, v);       // half-1 HBM loads in flight

    // conv0 (q -> f1)
    f32x4 acc[4][4] = {};
    QSTEP(A0, A1, w0p, 1, 0, acc)
    QSTEP(A1, A0, w0p, 2, 1, acc)
    QSTEP(A0, A1, w0p, 3, 2, acc)
    QSTEP(A1, A0, w0p, 4, 3, acc)        // prefetch s=4 across the barrier
    stage_write(1, sp, kq, v, xs);
    __syncthreads();
    QSTEP(A0, A1, w0p, 5, 4, acc)
    QSTEP(A1, A0, w0p, 6, 5, acc)
    QSTEP(A0, A1, w0p, 7, 6, acc)
    QSTEP(A1, A0, w1p, 0, 7, acc)        // prefetch conv1 s=0
    conv_epi_h16(acc, b0, f1 + obase, p0, wv, lane);

    // conv1 (v -> f2)
    {
        f32x4 acc2[4][4] = {};
        QSTEP(A0, A1, w1p, 1, 0, acc2)
        QSTEP(A1, A0, w1p, 2, 1, acc2)
        QSTEP(A0, A1, w1p, 3, 2, acc2)
        QSTEP(A1, A0, w1p, 4, 3, acc2)
        QSTEP(A0, A1, w1p, 5, 4, acc2)
        QSTEP(A1, A0, w1p, 6, 5, acc2)
        QSTEP(A0, A1, w1p, 7, 6, acc2)
        QSTEP(A1, A0, w2p, 0, 7, acc2)   // prefetch conv2 s=0
        conv_epi_h16(acc2, b1, f2 + obase, p0, wv, lane);
    }

    // conv2 (k -> g1)
    {
        f32x4 acc3[4][4] = {};
        QSTEP(A0, A1, w2p, 1, 0, acc3)
        QSTEP(A1, A0, w2p, 2, 1, acc3)
        QSTEP(A0, A1, w2p, 3, 2, acc3)
        QSTEP(A1, A0, w2p, 4, 3, acc3)
        QSTEP(A0, A1, w2p, 5, 4, acc3)
        QSTEP(A1, A0, w2p, 6, 5, acc3)
        QSTEP(A0, A1, w2p, 7, 6, acc3)
        QSTEP(A1, A0, w2p, 0, 7, acc3)   // tail prefetch harmless
        conv_epi_h16(acc3, b2, g1 + obase, p0, wv, lane);
    }
}

// ---------------------------------------------------------------------------
// Final conv: fp16 input, 1-term fp16 MFMA, A-prefetch, +bias +residual
// -> fp32. 32 KB LDS, plain bounds. EXACT round-16 form. grid: (HWI/64, B_)
// ---------------------------------------------------------------------------
__global__ __launch_bounds__(256)
void convY_k(const unsigned short* __restrict__ in, const float* __restrict__ res,
             const short* __restrict__ w, const float* __restrict__ bias,
             float* __restrict__ out)
{
    __shared__ short xs[64][256];   // 32 KB

    const int tid  = threadIdx.x;
    const int lane = tid & 63;
    const int wv   = tid >> 6;

    const int id    = blockIdx.y * gridDim.x + blockIdx.x;
    const int chunk = (gridDim.x * gridDim.y) >> 3;
    const int nid   = (id & 7) * chunk + (id >> 3);
    const int p0    = (nid & 63) * 64;
    const int b     = nid >> 6;

    const unsigned short* inb = in + (size_t)b * C_ * HWI + p0;
    const int sp = tid & 63, kq = tid >> 6;
    const int o16b = wv * 4;

    half8 A0[4], A1[4], Bq[4];
    load_a1(A0, w, 0, lane, o16b);

    unsigned short uv[32];

    // stage half 0
    #pragma unroll
    for (int r = 0; r < 4; ++r) {
        const int k8 = r * 4 + kq;
        #pragma unroll
        for (int j = 0; j < 8; ++j) uv[r * 8 + j] = inb[(size_t)(k8 * 8 + j) * HWI + sp];
    }
    #pragma unroll
    for (int r = 0; r < 4; ++r) {
        const int k8 = r * 4 + kq;
        short8 v8;
        #pragma unroll
        for (int j = 0; j < 8; ++j) v8[j] = (short)uv[r * 8 + j];
        *(short8*)&xs[sp][(k8 ^ (sp & 7)) * 8] = v8;
    }
    __syncthreads();

    // issue half-1 loads
    #pragma unroll
    for (int r = 0; r < 4; ++r) {
        const int k8 = 16 + r * 4 + kq;
        #pragma unroll
        for (int j = 0; j < 8; ++j) uv[r * 8 + j] = inb[(size_t)(k8 * 8 + j) * HWI + sp];
    }

    f32x4 acc[4][4] = {};
    QSTEP(A0, A1, w, 1, 0, acc)
    QSTEP(A1, A0, w, 2, 1, acc)
    QSTEP(A0, A1, w, 3, 2, acc)
    QSTEP(A1, A0, w, 4, 3, acc)

    #pragma unroll
    for (int r = 0; r < 4; ++r) {
        const int k8 = 16 + r * 4 + kq;
        short8 v8;
        #pragma unroll
        for (int j = 0; j < 8; ++j) v8[j] = (short)uv[r * 8 + j];
        *(short8*)&xs[sp][(k8 ^ (sp & 7)) * 8] = v8;
    }
    __syncthreads();

    QSTEP(A0, A1, w, 5, 4, acc)
    QSTEP(A1, A0, w, 6, 5, acc)
    QSTEP(A0, A1, w, 7, 6, acc)
    QSTEP(A1, A0, w, 0, 7, acc)   // tail harmless

    float* ob = out + (size_t)b * C_ * HWI;
    const float* rb = res + (size_t)b * C_ * HWI;
    const int pl = p0 + (lane & 15);
    #pragma unroll
    for (int i = 0; i < 4; ++i)
        #pragma unroll
        for (int r = 0; r < 4; ++r) {
            const int o = wv * 64 + i * 16 + (lane >> 4) * 4 + r;
            const float bz = bias[o];
            #pragma unroll
            for (int f = 0; f < 4; ++f) {
                const size_t off = (size_t)o * HWI + pl + f * 16;
                ob[off] = acc[i][f][r] + bz + rb[off];
            }
        }
}

// ---------------------------------------------------------------------------
// zgemmP: per-(b,c) z = f1 @ f2^T via 1-term fp16 MFMA, fused exp epilogue
// -> P = e^(z-SHIFT) bf16 (range!), LDS-transposed coalesced store.
// grid (C_, B_), 256 thr (4 waves), 16 KB LDS.
// ---------------------------------------------------------------------------
__global__ __launch_bounds__(256)
void zgemmP_k(const unsigned short* __restrict__ f1,
              const unsigned short* __restrict__ f2,
              unsigned short* __restrict__ P)
{
    __shared__ short am[64 * 64], bm[64 * 64];   // 16 KB

    const int tid = threadIdx.x, lane = tid & 63, wv = tid >> 6;
    const int c = blockIdx.x, b = blockIdx.y;
    const size_t base = ((size_t)b * C_ + c) * HWI;

    const int r = tid >> 2, q8 = (tid & 3) * 2;
    {
        const size_t g0 = base + r * 64 + q8 * 8;
        short8 v0 = *(const short8*)(f1 + g0), v1 = *(const short8*)(f1 + g0 + 8);
        short8 u0 = *(const short8*)(f2 + g0), u1 = *(const short8*)(f2 + g0 + 8);
        const int c0 = (q8 ^ (r & 7)) * 8, c1 = ((q8 + 1) ^ (r & 7)) * 8;
        *(short8*)&am[r * 64 + c0] = v0;  *(short8*)&am[r * 64 + c1] = v1;
        *(short8*)&bm[r * 64 + c0] = u0;  *(short8*)&bm[r * 64 + c1] = u1;
    }
    __syncthreads();

    f32x4 acc[4] = {};
    const int m = wv * 16 + (lane & 15);
    #pragma unroll
    for (int s = 0; s < 2; ++s) {
        const int k8 = s * 4 + (lane >> 4);
        half8 a = *(const half8*)&am[m * 64 + (k8 ^ (m & 7)) * 8];
        #pragma unroll
        for (int nf = 0; nf < 4; ++nf) {
            const int n = nf * 16 + (lane & 15);
            half8 bb = *(const half8*)&bm[n * 64 + (k8 ^ (n & 7)) * 8];
            acc[nf] = MFMAH(a, bb, acc[nf]);
        }
    }
    __syncthreads();   // all frag reads done; reuse am as transpose buffer

    short* pt = am;
    #pragma unroll
    for (int nf = 0; nf < 4; ++nf)
        #pragma unroll
        for (int rr = 0; rr < 4; ++rr) {
            const int h = wv * 16 + (lane >> 4) * 4 + rr;
            const int g = nf * 16 + (lane & 15);
            const float pv = __expf(acc[nf][rr] - SHIFT);
            pt[h * 64 + (((g >> 3) ^ (h & 7)) * 8) + (g & 7)] = (short)f2bf(pv);
        }
    __syncthreads();
    {
        const size_t g0 = base + r * 64 + q8 * 8;
        const int c0 = (q8 ^ (r & 7)) * 8, c1 = ((q8 + 1) ^ (r & 7)) * 8;
        *(short8*)(P + g0)     = *(const short8*)&pt[r * 64 + c0];
        *(short8*)(P + g0 + 8) = *(const short8*)&pt[r * 64 + c1];
    }
}

// ---------------------------------------------------------------------------
// statsP: sr[b,p] = 1 / sum_c P[b,c,p]   (P bf16)
// ---------------------------------------------------------------------------
__global__ __launch_bounds__(256)
void statsP_k(const unsigned short* __restrict__ P, float* __restrict__ sr)
{
    const int qidx = blockIdx.x * 256 + threadIdx.x;
    const int b = qidx >> 12, p = qidx & 4095;
    const unsigned short* pp = P + (size_t)b * C_ * HWI + p;
    float s = 0.f;
    for (int c0 = 0; c0 < C_; c0 += 8) {
        float e = 0.f;
        #pragma unroll
        for (int j = 0; j < 8; ++j) e += bf2f(pp[(size_t)(c0 + j) * HWI]);
        s += e;
    }
    sr[qidx] = 1.0f / s;
}

// ---------------------------------------------------------------------------
// pvP: out1 = (P .* sr) @ g1 via 1-term fp16 MFMA. P*sr in [0,1] -> fp16.
// grid (C_, B_), 16 KB LDS. out1 fp16.
// ---------------------------------------------------------------------------
__global__ __launch_bounds__(256)
void pvP_k(const unsigned short* __restrict__ P, const float* __restrict__ sr,
           const unsigned short* __restrict__ g1, unsigned short* __restrict__ out1)
{
    __shared__ short pa[64 * 64], gb[64 * 64];

    const int tid = threadIdx.x, lane = tid & 63, wv = tid >> 6;
    const int c = blockIdx.x, b = blockIdx.y;
    const size_t base = ((size_t)b * C_ + c) * HWI;

    const int r = tid >> 2, q8 = (tid & 3) * 2;
    {   // A = P' = P * sr  (fp16)  [h][g]
        const size_t g0 = base + r * 64 + q8 * 8;
        const float* srp = sr + (size_t)b * HWI + r * 64 + q8 * 8;
        short8 p0 = *(const short8*)(P + g0), p1 = *(const short8*)(P + g0 + 8);
        short8 w0, w1;
        #pragma unroll
        for (int j = 0; j < 8; ++j) {
            w0[j] = (short)f2h(bf2f((unsigned short)p0[j]) * srp[j]);
            w1[j] = (short)f2h(bf2f((unsigned short)p1[j]) * srp[8 + j]);
        }
        const int c0 = (q8 ^ (r & 7)) * 8, c1 = ((q8 + 1) ^ (r & 7)) * 8;
        *(short8*)&pa[r * 64 + c0] = w0;
        *(short8*)&pa[r * 64 + c1] = w1;
    }
    {   // B = g1^T : gb[w][g]
        const int w = tid & 63, kq = tid >> 6;
        short8 t0, t1;
        #pragma unroll
        for (int j = 0; j < 8; ++j) t0[j] = (short)g1[base + (size_t)(kq * 16 + j) * 64 + w];
        #pragma unroll
        for (int j = 0; j < 8; ++j) t1[j] = (short)g1[base + (size_t)(kq * 16 + 8 + j) * 64 + w];
        const int c0 = ((kq * 2) ^ (w & 7)) * 8, c1 = ((kq * 2 + 1) ^ (w & 7)) * 8;
        *(short8*)&gb[w * 64 + c0] = t0;
        *(short8*)&gb[w * 64 + c1] = t1;
    }
    __syncthreads();

    f32x4 acc[4] = {};
    const int m = wv * 16 + (lane & 15);
    #pragma unroll
    for (int s = 0; s < 2; ++s) {
        const int k8 = s * 4 + (lane >> 4);
        half8 aa = *(const half8*)&pa[m * 64 + (k8 ^ (m & 7)) * 8];
        #pragma unroll
        for (int nf = 0; nf < 4; ++nf) {
            const int n = nf * 16 + (lane & 15);
            half8 bb = *(const half8*)&gb[n * 64 + (k8 ^ (n & 7)) * 8];
            acc[nf] = MFMAH(aa, bb, acc[nf]);
        }
    }
    __syncthreads();

    short* ot = pa;
    #pragma unroll
    for (int nf = 0; nf < 4; ++nf)
        #pragma unroll
        for (int rr = 0; rr < 4; ++rr) {
            const int h = wv * 16 + (lane >> 4) * 4 + rr;
            const int w = nf * 16 + (lane & 15);
            ot[h * 64 + (((w >> 3) ^ (h & 7)) * 8) + (w & 7)] = (short)f2h(acc[nf][rr]);
        }
    __syncthreads();
    {
        const size_t g0 = base + r * 64 + q8 * 8;
        const int c0 = (q8 ^ (r & 7)) * 8, c1 = ((q8 + 1) ^ (r & 7)) * 8;
        *(short8*)(out1 + g0)     = *(const short8*)&ot[r * 64 + c0];
        *(short8*)(out1 + g0 + 8) = *(const short8*)&ot[r * 64 + c1];
    }
}

// ---------------------------------------------------------------------------
extern "C" void kernel_launch(void* const* d_in, const int* in_sizes, int n_in,
                              void* d_out, int out_size, void* d_ws, size_t ws_size,
                              hipStream_t stream)
{
    (void)in_sizes; (void)n_in; (void)out_size;
    const float* x  = (const float*)d_in[0];
    const float* wq = (const float*)d_in[1];
    const float* bq = (const float*)d_in[2];
    const float* wv = (const float*)d_in[3];
    const float* bv = (const float*)d_in[4];
    const float* wk = (const float*)d_in[5];
    const float* bk = (const float*)d_in[6];
    const float* wy = (const float*)d_in[7];
    const float* by = (const float*)d_in[8];
    float* out = (float*)d_out;

    const size_t N  = (size_t)B_ * C_ * HWI;   // 33,554,432
    const size_t NS = (size_t)B_ * HWI;        // 131,072

    char* wsb = (char*)d_ws;
    short* wsp = (short*)wsb;
    const size_t wbytes = 4 * (size_t)NW * sizeof(short);   // 512 KB
    char* fb = wsb + wbytes;

    dim3 blk(256);
    hipLaunchKernelGGL(wsingle4_k, dim3(32, 4), blk, 0, stream, wq, wv, wk, wy, wsp);
    const short* wqvk = wsp;                 // q,v,k (3 x NW)
    const short* wyp  = wsp + 3 * (size_t)NW;

    dim3 cgrid(HWI / 64, B_);     // 2048 blocks
    dim3 zgrid(C_, B_);           // 8192 blocks
    dim3 sgrid((unsigned)(NS / 256));

    // Layout A: everything in ws. Layout B: f2,P live in d_out (dead until convY)
    const bool bigA = ws_size >= wbytes + 8 * N + 4 * NS;

    unsigned short *f1, *f2, *g1, *P, *o1;
    float* sr;
    if (bigA) {
        f1 = (unsigned short*)fb;
        f2 = (unsigned short*)(fb + 2 * N);
        g1 = (unsigned short*)(fb + 4 * N);
        P  = (unsigned short*)(fb + 6 * N);
        sr = (float*)(fb + 8 * N);
    } else {
        f1 = (unsigned short*)fb;
        g1 = (unsigned short*)(fb + 2 * N);
        sr = (float*)(fb + 4 * N);
        f2 = (unsigned short*)d_out;          // d_out = 4N bytes total
        P  = (unsigned short*)d_out + N;
    }
    o1 = f1;   // reuse (f1 dead after zgemmP)

    hipLaunchKernelGGL(convQVK_k, cgrid, blk, 0, stream,
                       x, wqvk, bq, bv, bk, f1, f2, g1);
    hipLaunchKernelGGL(zgemmP_k, zgrid, blk, 0, stream, f1, f2, P);
    hipLaunchKernelGGL(statsP_k, sgrid, blk, 0, stream, P, sr);
    hipLaunchKernelGGL(pvP_k,    zgrid, blk, 0, stream, P, sr, g1, o1);
    hipLaunchKernelGGL(convY_k,  cgrid, blk, 0, stream, o1, x, wyp, by, out);
}